// Round 1
// baseline (1216.741 us; speedup 1.0000x reference)
//
#include <hip/hip_runtime.h>
#include <cmath>

// ---- problem constants ----
constexpr int BD   = 8;
constexpr int CIN  = 192;
constexpr int HDIM = 64;
constexpr int WDIM = 64;
constexpr int HW   = HDIM * WDIM;          // 4096
constexpr int NIMG = BD * HW;              // 32768
constexpr int HID  = 256;
constexpr int DE   = 64;
constexpr int NCLS = 8192;
constexpr int NE   = 131072;

#define EPSW 1e-4f
// mp_cat(t=0.5, Na=256, Nb=64): Cc=sqrt(640)
#define ALPHA 0.7905694150420949f   // Cc/sqrt(256)*0.5
#define BETA  1.5811388300841898f   // Cc/sqrt(64)*0.5
#define SILU_INV 1.6778523489932886f // 1/0.596
#define INV_SQRT2 0.7071067811865476f

__device__ __forceinline__ float wave_red_sum(float v) {
  #pragma unroll
  for (int off = 32; off > 0; off >>= 1) v += __shfl_xor(v, off, 64);
  return v;
}

// ---- weight normalization: out[r, ooff + f] = w[r,f] / (EPS*sqrt(F) + ||w_r||) ----
__global__ void wnorm_k(const float* __restrict__ w, float* __restrict__ out,
                        int F, int ostride, int ooff) {
  const int row  = blockIdx.x;
  const int lane = threadIdx.x;
  const float* wr = w + (size_t)row * F;
  float ss = 0.f;
  for (int f = lane; f < F; f += 64) { float v = wr[f]; ss += v * v; }
  ss = wave_red_sum(ss);
  const float scale = 1.0f / (EPSW * sqrtf((float)F) + sqrtf(ss));
  float* o = out + (size_t)row * ostride + ooff;
  for (int f = lane; f < F; f += 64) o[f] = wr[f] * scale;
}

// ---- per-dst edge counts (both graphs in one pass) ----
__global__ void count_k(const int* __restrict__ d1, const int* __restrict__ d2,
                        float* __restrict__ c1, float* __restrict__ c2, int E) {
  int e = blockIdx.x * 256 + threadIdx.x;
  if (e < E) {
    atomicAdd(&c1[d1[e]], 1.0f);
    atomicAdd(&c2[d2[e]], 1.0f);
  }
}

__global__ void inv_k(float* __restrict__ c, int n) {
  int i = blockIdx.x * 256 + threadIdx.x;
  if (i < n) c[i] = 1.0f / fmaxf(c[i], 1.0f);
}

// ---- in-place mp_silu ----
__global__ void silu_k(float* __restrict__ h, int n) {
  int i = blockIdx.x * 256 + threadIdx.x;
  if (i < n) {
    float v = h[i];
    h[i] = (v / (1.0f + __expf(-v))) * SILU_INV;
  }
}

// ---- scatter-add of scaled messages: agg[dst] += [ALPHA*H[src], BETA*EA[e]] ----
__global__ __launch_bounds__(256) void scatter_k(
    const float* __restrict__ Hsrc, const float* __restrict__ EA,
    const int* __restrict__ src, const int* __restrict__ dst,
    float* __restrict__ agg, int E) {
  const int e = blockIdx.x * 4 + (threadIdx.x >> 6);
  const int lane = threadIdx.x & 63;
  if (e >= E) return;
  const int s = src[e];
  const int d = dst[e];
  float* out = agg + (size_t)d * 320;
  const float* hs = Hsrc + (size_t)s * 256;
  const float* ep = EA + (size_t)e * 64;
  #pragma unroll
  for (int t = 0; t < 5; ++t) {
    int k = lane + t * 64;
    float v = (t < 4) ? ALPHA * hs[k] : BETA * ep[k - 256];
    atomicAdd(&out[k], v);
  }
}

// ---- row L2 normalize of (v/sqrt(2)), rows of 256 ----
__global__ __launch_bounds__(256) void rownorm_k(float* __restrict__ X, int nrows) {
  const int row  = blockIdx.x * 4 + (threadIdx.x >> 6);
  const int lane = threadIdx.x & 63;
  float4 v = *reinterpret_cast<float4*>(&X[(size_t)row * 256 + lane * 4]);
  v.x *= INV_SQRT2; v.y *= INV_SQRT2; v.z *= INV_SQRT2; v.w *= INV_SQRT2;
  float ss = v.x * v.x + v.y * v.y + v.z * v.z + v.w * v.w;
  ss = wave_red_sum(ss);
  const float scale = 1.0f / fmaxf(sqrtf(ss), 1e-12f);
  v.x *= scale; v.y *= scale; v.z *= scale; v.w *= scale;
  *reinterpret_cast<float4*>(&X[(size_t)row * 256 + lane * 4]) = v;
}

// ---- generic tiled fp32 GEMM: C[M,256] = A[M,K] @ B[256,K]^T ----
// a_mode: 0 = plain row-major [M,K]
//         1 = x tensor [B,192,64,64] viewed as [NIMG,192]
//         2 = concat: k<320 -> agg[M,320]*invc[row]; k>=320 -> A2[M,256]
// c_mode: 0 = plain [M,256]; 1 = img tensor: C[((r>>12)*256 + col)*4096 + (r&4095)]
__global__ __launch_bounds__(256) void gemm_k(
    const float* __restrict__ A, const float* __restrict__ A2,
    const float* __restrict__ invc, const float* __restrict__ B,
    float* __restrict__ C, int M, int K, int a_mode, int c_mode) {
  __shared__ float As[16][64];
  __shared__ float Bs[16][64];
  const int tid = threadIdx.x;
  const int tx = tid & 15, ty = tid >> 4;
  const int row0 = blockIdx.x * 64, col0 = blockIdx.y * 64;
  const int lr = tid >> 2;            // 0..63
  const int lk = (tid & 3) * 4;       // 0,4,8,12
  const int gr = row0 + lr;
  const float inv = (a_mode == 2) ? invc[gr] : 1.0f;
  float acc[4][4] = {};

  for (int k0 = 0; k0 < K; k0 += 16) {
    float4 av;
    if (a_mode == 0) {
      av = *reinterpret_cast<const float4*>(&A[(size_t)gr * K + k0 + lk]);
    } else if (a_mode == 1) {
      const int b = gr >> 12, hw = gr & 4095;
      const float* base = A + ((size_t)b * CIN + (k0 + lk)) * HW + hw;
      av.x = base[0]; av.y = base[HW]; av.z = base[2 * HW]; av.w = base[3 * HW];
    } else {
      if (k0 < 320) {
        av = *reinterpret_cast<const float4*>(&A[(size_t)gr * 320 + k0 + lk]);
        av.x *= inv; av.y *= inv; av.z *= inv; av.w *= inv;
      } else {
        av = *reinterpret_cast<const float4*>(&A2[(size_t)gr * 256 + (k0 - 320) + lk]);
      }
    }
    As[lk + 0][lr] = av.x; As[lk + 1][lr] = av.y;
    As[lk + 2][lr] = av.z; As[lk + 3][lr] = av.w;

    float4 bv = *reinterpret_cast<const float4*>(&B[(size_t)(col0 + lr) * K + k0 + lk]);
    Bs[lk + 0][lr] = bv.x; Bs[lk + 1][lr] = bv.y;
    Bs[lk + 2][lr] = bv.z; Bs[lk + 3][lr] = bv.w;

    __syncthreads();
    #pragma unroll
    for (int kk = 0; kk < 16; ++kk) {
      float4 a4 = *reinterpret_cast<const float4*>(&As[kk][ty * 4]);
      float4 b4 = *reinterpret_cast<const float4*>(&Bs[kk][tx * 4]);
      float ar[4] = {a4.x, a4.y, a4.z, a4.w};
      float br[4] = {b4.x, b4.y, b4.z, b4.w};
      #pragma unroll
      for (int i = 0; i < 4; ++i)
        #pragma unroll
        for (int j = 0; j < 4; ++j)
          acc[i][j] = fmaf(ar[i], br[j], acc[i][j]);
    }
    __syncthreads();
  }

  if (c_mode == 0) {
    #pragma unroll
    for (int i = 0; i < 4; ++i) {
      float4 v = make_float4(acc[i][0], acc[i][1], acc[i][2], acc[i][3]);
      *reinterpret_cast<float4*>(&C[(size_t)(row0 + ty * 4 + i) * 256 + col0 + tx * 4]) = v;
    }
  } else {
    #pragma unroll
    for (int i = 0; i < 4; ++i) {
      const int rr = row0 + ty * 4 + i;
      const int b = rr >> 12, hw = rr & 4095;
      #pragma unroll
      for (int j = 0; j < 4; ++j)
        C[((size_t)b * 256 + (col0 + tx * 4 + j)) * HW + hw] = acc[i][j];
    }
  }
}

extern "C" void kernel_launch(void* const* d_in, const int* in_sizes, int n_in,
                              void* d_out, int out_size, void* d_ws, size_t ws_size,
                              hipStream_t stream) {
  const float* x        = (const float*)d_in[0];
  const float* class_x  = (const float*)d_in[1];
  const float* ea_c2i   = (const float*)d_in[2];
  const float* ea_i2c   = (const float*)d_in[3];
  const float* w_in_img = (const float*)d_in[4];
  const float* w_in_cls = (const float*)d_in[5];
  const float* wl_c2i_1 = (const float*)d_in[6];
  const float* wr_c2i_1 = (const float*)d_in[7];
  const float* wl_i2c_1 = (const float*)d_in[8];
  const float* wr_i2c_1 = (const float*)d_in[9];
  const float* wl_c2i_2 = (const float*)d_in[10];
  const float* wr_c2i_2 = (const float*)d_in[11];
  const float* wl_i2c_2 = (const float*)d_in[12];
  const float* wr_i2c_2 = (const float*)d_in[13];
  const float* w_out_img = (const float*)d_in[14];
  const float* w_out_cls = (const float*)d_in[15];
  const int* src_c2i = (const int*)d_in[16];
  const int* dst_c2i = (const int*)d_in[17];
  const int* src_i2c = (const int*)d_in[18];
  const int* dst_i2c = (const int*)d_in[19];

  float* ws = (float*)d_ws;
  size_t off = 0;
  auto alloc = [&](size_t n) { float* p = ws + off; off += n; return p; };

  float* HA_img = alloc((size_t)NIMG * HID);
  float* HB_img = alloc((size_t)NIMG * HID);
  float* HA_cls = alloc((size_t)NCLS * HID);
  float* HB_cls = alloc((size_t)NCLS * HID);
  float* agg_img = alloc((size_t)NIMG * 320);
  float* agg_cls = alloc((size_t)NCLS * 320);
  float* inv_img = alloc(NIMG);           // adjacent to inv_cls
  float* inv_cls = alloc(NCLS);
  float* wn_in_img = alloc(256 * 192);
  float* wn_in_cls = alloc(256 * 128);
  float* wcat0 = alloc(256 * 576);        // layer1 c2i: [wl | wr]
  float* wcat1 = alloc(256 * 576);        // layer1 i2c
  float* wcat2 = alloc(256 * 576);        // layer2 c2i
  float* wcat3 = alloc(256 * 576);        // layer2 i2c
  float* wn_out_img = alloc(256 * 256);
  float* wn_out_cls = alloc(256 * 256);

  const dim3 blk(256);

  // ---- weight normalization ----
  wnorm_k<<<256, 64, 0, stream>>>(w_in_img, wn_in_img, 192, 192, 0);
  wnorm_k<<<256, 64, 0, stream>>>(w_in_cls, wn_in_cls, 128, 128, 0);
  wnorm_k<<<256, 64, 0, stream>>>(wl_c2i_1, wcat0, 320, 576, 0);
  wnorm_k<<<256, 64, 0, stream>>>(wr_c2i_1, wcat0, 256, 576, 320);
  wnorm_k<<<256, 64, 0, stream>>>(wl_i2c_1, wcat1, 320, 576, 0);
  wnorm_k<<<256, 64, 0, stream>>>(wr_i2c_1, wcat1, 256, 576, 320);
  wnorm_k<<<256, 64, 0, stream>>>(wl_c2i_2, wcat2, 320, 576, 0);
  wnorm_k<<<256, 64, 0, stream>>>(wr_c2i_2, wcat2, 256, 576, 320);
  wnorm_k<<<256, 64, 0, stream>>>(wl_i2c_2, wcat3, 320, 576, 0);
  wnorm_k<<<256, 64, 0, stream>>>(wr_i2c_2, wcat3, 256, 576, 320);
  wnorm_k<<<256, 64, 0, stream>>>(w_out_img, wn_out_img, 256, 256, 0);
  wnorm_k<<<256, 64, 0, stream>>>(w_out_cls, wn_out_cls, 256, 256, 0);

  // ---- per-dst counts (fixed across layers) ----
  hipMemsetAsync(inv_img, 0, (size_t)(NIMG + NCLS) * sizeof(float), stream);
  count_k<<<NE / 256, blk, 0, stream>>>(dst_c2i, dst_i2c, inv_img, inv_cls, NE);
  inv_k<<<(NIMG + NCLS) / 256, blk, 0, stream>>>(inv_img, NIMG + NCLS);

  // ---- input projections ----
  gemm_k<<<dim3(NIMG / 64, 4), blk, 0, stream>>>(x, nullptr, nullptr, wn_in_img,
                                                 HA_img, NIMG, 192, 1, 0);
  gemm_k<<<dim3(NCLS / 64, 4), blk, 0, stream>>>(class_x, nullptr, nullptr, wn_in_cls,
                                                 HA_cls, NCLS, 128, 0, 0);

  // ---- layers ----
  float* Ximg = HA_img; float* Xcls = HA_cls;
  float* Yimg = HB_img; float* Ycls = HB_cls;
  const float* wc2i[2] = {wcat0, wcat2};
  const float* wi2c[2] = {wcat1, wcat3};
  for (int l = 0; l < 2; ++l) {
    silu_k<<<(size_t)NIMG * HID / 256, blk, 0, stream>>>(Ximg, NIMG * HID);
    silu_k<<<(size_t)NCLS * HID / 256, blk, 0, stream>>>(Xcls, NCLS * HID);

    // cls -> img
    hipMemsetAsync(agg_img, 0, (size_t)NIMG * 320 * sizeof(float), stream);
    scatter_k<<<NE / 4, blk, 0, stream>>>(Xcls, ea_c2i, src_c2i, dst_c2i, agg_img, NE);
    gemm_k<<<dim3(NIMG / 64, 4), blk, 0, stream>>>(agg_img, Ximg, inv_img, wc2i[l],
                                                   Yimg, NIMG, 576, 2, 0);
    rownorm_k<<<NIMG / 4, blk, 0, stream>>>(Yimg, NIMG);

    // img -> cls (uses pre-layer a_img = silu'd Ximg)
    hipMemsetAsync(agg_cls, 0, (size_t)NCLS * 320 * sizeof(float), stream);
    scatter_k<<<NE / 4, blk, 0, stream>>>(Ximg, ea_i2c, src_i2c, dst_i2c, agg_cls, NE);
    gemm_k<<<dim3(NCLS / 64, 4), blk, 0, stream>>>(agg_cls, Xcls, inv_cls, wi2c[l],
                                                   Ycls, NCLS, 576, 2, 0);
    rownorm_k<<<NCLS / 4, blk, 0, stream>>>(Ycls, NCLS);

    // ping-pong
    float* t;
    t = Ximg; Ximg = Yimg; Yimg = t;
    t = Xcls; Xcls = Ycls; Ycls = t;
  }

  // ---- output projections ----
  float* out_img = (float*)d_out;
  float* out_cls = (float*)d_out + (size_t)NIMG * HID;
  gemm_k<<<dim3(NIMG / 64, 4), blk, 0, stream>>>(Ximg, nullptr, nullptr, wn_out_img,
                                                 out_img, NIMG, 256, 0, 1);
  gemm_k<<<dim3(NCLS / 64, 4), blk, 0, stream>>>(Xcls, nullptr, nullptr, wn_out_cls,
                                                 out_cls, NCLS, 256, 0, 0);
}